// Round 3
// baseline (260.732 us; speedup 1.0000x reference)
//
#include <hip/hip_runtime.h>

#define DIM 4096
#define BLK 256

__device__ __forceinline__ float dot4(float4 a, float4 b) {
  return a.x * b.x + a.y * b.y + a.z * b.z + a.w * b.w;
}

__device__ __forceinline__ float wave_reduce(float s) {
#pragma unroll
  for (int off = 32; off > 0; off >>= 1) s += __shfl_down(s, off);
  return s;
}

// ---------- kernel 1: vecprep + zero accumulators ----------
// grid 4 x 256 threads = 1024 float4 lanes
__global__ void __launch_bounds__(BLK) prep_kernel(
    const float* __restrict__ x, const float* __restrict__ sxx,
    const float* __restrict__ tmk, const float* __restrict__ tmv,
    const float* __restrict__ tmr,
    float* __restrict__ xk, float* __restrict__ xv, float* __restrict__ xr,
    float* __restrict__ k, float* __restrict__ v, float* __restrict__ rr,
    float* __restrict__ y) {
  int i = blockIdx.x * BLK + threadIdx.x;  // float4 index, 0..1023
  const float4* x4 = (const float4*)x;
  const float4* s4 = (const float4*)sxx;
  const float4* mk4 = (const float4*)tmk;
  const float4* mv4 = (const float4*)tmv;
  const float4* mr4 = (const float4*)tmr;
  float4 xi = x4[i], si = s4[i];
  float4 mk = mk4[i], mv = mv4[i], mr = mr4[i];
  float4 ok, ov, orr;
  ok.x = fmaf(xi.x - si.x, mk.x, si.x); ok.y = fmaf(xi.y - si.y, mk.y, si.y);
  ok.z = fmaf(xi.z - si.z, mk.z, si.z); ok.w = fmaf(xi.w - si.w, mk.w, si.w);
  ov.x = fmaf(xi.x - si.x, mv.x, si.x); ov.y = fmaf(xi.y - si.y, mv.y, si.y);
  ov.z = fmaf(xi.z - si.z, mv.z, si.z); ov.w = fmaf(xi.w - si.w, mv.w, si.w);
  orr.x = fmaf(xi.x - si.x, mr.x, si.x); orr.y = fmaf(xi.y - si.y, mr.y, si.y);
  orr.z = fmaf(xi.z - si.z, mr.z, si.z); orr.w = fmaf(xi.w - si.w, mr.w, si.w);
  ((float4*)xk)[i] = ok;
  ((float4*)xv)[i] = ov;
  ((float4*)xr)[i] = orr;
  float4 z = make_float4(0.f, 0.f, 0.f, 0.f);
  ((float4*)k)[i] = z;
  ((float4*)v)[i] = z;
  ((float4*)rr)[i] = z;
  ((float4*)y)[i] = z;
}

// ---------- kernel 2: split-K 3-matrix matvec, atomic reduction ----------
// grid 2048 x 256 -> 8192 waves. wave wid: c = wid&3 (column chunk of 1024
// floats), r0 = wid>>2 (0..2047); handles rows {r0, r0+2048} x 3 matrices.
__global__ void __launch_bounds__(BLK) matvec3_split(
    const float* __restrict__ wr, const float* __restrict__ wk,
    const float* __restrict__ wv,
    const float* __restrict__ xr, const float* __restrict__ xk,
    const float* __restrict__ xv,
    float* __restrict__ rr, float* __restrict__ k, float* __restrict__ v) {
  const int lane = threadIdx.x & 63;
  const int wid = blockIdx.x * (BLK / 64) + (threadIdx.x >> 6);
  const int c = wid & 3;
  const int r0 = wid >> 2;
  const int col = c * 256 + lane;  // float4 index within a row

  const float4* wmat[3] = {(const float4*)wr, (const float4*)wk, (const float4*)wv};
  const float4* xvec[3] = {(const float4*)xr, (const float4*)xk, (const float4*)xv};
  float* ovec[3] = {rr, k, v};

#pragma unroll
  for (int m = 0; m < 3; ++m) {
    const float4* xp = xvec[m];
    float4 xf0 = xp[col];
    float4 xf1 = xp[col + 64];
    float4 xf2 = xp[col + 128];
    float4 xf3 = xp[col + 192];
#pragma unroll
    for (int h = 0; h < 2; ++h) {
      const int r = r0 + h * 2048;
      const float4* wrow = wmat[m] + (size_t)r * 1024 + col;
      float s = dot4(wrow[0], xf0);
      s += dot4(wrow[64], xf1);
      s += dot4(wrow[128], xf2);
      s += dot4(wrow[192], xf3);
      s = wave_reduce(s);
      if (lane == 0) atomicAdd(ovec[m] + r, s);
    }
  }
}

// ---------- kernel 3: elementwise WKV + state update ----------
__global__ void __launch_bounds__(BLK) wkv_kernel(
    const float* __restrict__ x, const float* __restrict__ aa,
    const float* __restrict__ bb, const float* __restrict__ pp,
    const float* __restrict__ t_decay, const float* __restrict__ t_first,
    const float* __restrict__ k, const float* __restrict__ v,
    const float* __restrict__ rr,
    float* __restrict__ rab, float* __restrict__ out_x,
    float* __restrict__ out_aa, float* __restrict__ out_bb,
    float* __restrict__ out_pp) {
  int i = blockIdx.x * BLK + threadIdx.x;
  float kk = k[i], vv = v[i];
  float r = 1.0f / (1.0f + expf(-rr[i]));
  float ppi = pp[i], aai = aa[i], bbi = bb[i];
  float ww = t_first[i] + kk;
  float p = fmaxf(ppi, ww);
  float e1 = expf(ppi - p), e2 = expf(ww - p);
  float a = e1 * aai + e2 * vv;
  float b = e1 * bbi + e2;
  rab[i] = r * (a / b);
  float ww2 = ppi + t_decay[i];
  float p2 = fmaxf(ww2, kk);
  float e1b = expf(ww2 - p2), e2b = expf(kk - p2);
  out_x[i] = x[i];
  out_aa[i] = e1b * aai + e2b * vv;
  out_bb[i] = e1b * bbi + e2b;
  out_pp[i] = p2;
}

// ---------- kernel 4: split-K output matvec ----------
// grid 2048 x 256 -> 8192 waves; wave handles rows {r0, r0+2048}, chunk c.
__global__ void __launch_bounds__(BLK) matvec_out_split(
    const float* __restrict__ w, const float* __restrict__ xin,
    float* __restrict__ y) {
  const int lane = threadIdx.x & 63;
  const int wid = blockIdx.x * (BLK / 64) + (threadIdx.x >> 6);
  const int c = wid & 3;
  const int r0 = wid >> 2;
  const int col = c * 256 + lane;

  const float4* xp = (const float4*)xin;
  float4 xf0 = xp[col];
  float4 xf1 = xp[col + 64];
  float4 xf2 = xp[col + 128];
  float4 xf3 = xp[col + 192];
#pragma unroll
  for (int h = 0; h < 2; ++h) {
    const int r = r0 + h * 2048;
    const float4* wrow = (const float4*)w + (size_t)r * 1024 + col;
    float s = dot4(wrow[0], xf0);
    s += dot4(wrow[64], xf1);
    s += dot4(wrow[128], xf2);
    s += dot4(wrow[192], xf3);
    s = wave_reduce(s);
    if (lane == 0) atomicAdd(y + r, s);
  }
}

extern "C" void kernel_launch(void* const* d_in, const int* in_sizes, int n_in,
                              void* d_out, int out_size, void* d_ws, size_t ws_size,
                              hipStream_t stream) {
  const float* x       = (const float*)d_in[0];
  const float* sxx     = (const float*)d_in[1];
  const float* aa      = (const float*)d_in[2];
  const float* bb      = (const float*)d_in[3];
  const float* pp      = (const float*)d_in[4];
  const float* w_key   = (const float*)d_in[5];
  const float* w_val   = (const float*)d_in[6];
  const float* w_rec   = (const float*)d_in[7];
  const float* w_out   = (const float*)d_in[8];
  const float* t_decay = (const float*)d_in[9];
  const float* t_first = (const float*)d_in[10];
  const float* t_mix_k = (const float*)d_in[11];
  const float* t_mix_v = (const float*)d_in[12];
  const float* t_mix_r = (const float*)d_in[13];

  float* out    = (float*)d_out;
  float* y      = out;            // output 0
  float* out_x  = out + DIM;      // output 1 (new state_xx = x)
  float* out_aa = out + 2 * DIM;  // output 2
  float* out_bb = out + 3 * DIM;  // output 3
  float* out_pp = out + 4 * DIM;  // output 4

  float* ws  = (float*)d_ws;
  float* xk  = ws;
  float* xv  = ws + DIM;
  float* xr  = ws + 2 * DIM;
  float* k   = ws + 3 * DIM;
  float* v   = ws + 4 * DIM;
  float* rr  = ws + 5 * DIM;
  float* rab = ws + 6 * DIM;

  prep_kernel<<<DIM / 4 / BLK, BLK, 0, stream>>>(
      x, sxx, t_mix_k, t_mix_v, t_mix_r, xk, xv, xr, k, v, rr, y);
  matvec3_split<<<2048, BLK, 0, stream>>>(w_rec, w_key, w_val, xr, xk, xv,
                                          rr, k, v);
  wkv_kernel<<<DIM / BLK, BLK, 0, stream>>>(x, aa, bb, pp, t_decay, t_first,
                                            k, v, rr, rab, out_x, out_aa,
                                            out_bb, out_pp);
  matvec_out_split<<<2048, BLK, 0, stream>>>(w_out, rab, y);
}